// Round 8
// baseline (32.484 us; speedup 1.0000x reference)
//
#include <hip/hip_runtime.h>
#include <math.h>

#define THREADS 256
#define BLOCKS  2048
#define STRIDE  (BLOCKS * THREADS)
#define FTHREADS 1024

__device__ __forceinline__ float wave_reduce(float v) {
    #pragma unroll
    for (int off = 32; off > 0; off >>= 1)
        v += __shfl_down(v, off, 64);
    return v;
}

__device__ __forceinline__ void accum_elem(float pp, float pt, float md, float tg,
                                           float V, float& phys, float& lm) {
    constexpr float P_ATM    = 0.101325f;
    constexpr float BETA     = 1466.96f;
    constexpr float INV_BETA = 1.0f / 1466.96f;
    constexpr float R_FRAC   = 0.005f / 0.995f;
    constexpr float C_RP     = R_FRAC * P_ATM;
    constexpr float RHO_MIX  = 851.6f + 1.225f * R_FRAC;
    constexpr float PT_EPS   = 1e-12f;

    float p_used  = fmaxf(pp * 0.1f, 1.0f);
    float inv_pu  = __builtin_amdgcn_rcpf(p_used);
    float p_denom = C_RP * inv_pu;
    float p_ratio = p_denom * inv_pu;
    float e       = __expf((P_ATM - p_used) * INV_BETA) * INV_BETA;
    float denom   = BETA * e + p_denom;
    float inv_d   = __builtin_amdgcn_rcpf(denom);
    float drho    = RHO_MIX * (e + p_ratio) * inv_d * inv_d;

    float res  = V * drho * pt - md;
    bool  m    = fabsf(pt) >= PT_EPS;
    phys += m ? fabsf(res)     : 0.0f;
    lm   += m ? fabsf(tg - pp) : 0.0f;
}

__device__ __forceinline__ void accum_vec4(const float4& a, const float4& b,
                                           const float4& c, const float4& d,
                                           float V, float& phys, float& lm) {
    accum_elem(a.x, b.x, c.x, d.x, V, phys, lm);
    accum_elem(a.y, b.y, c.y, d.y, V, phys, lm);
    accum_elem(a.z, b.z, c.z, d.z, V, phys, lm);
    accum_elem(a.w, b.w, c.w, d.w, V, phys, lm);
}

// ---------------- Kernel 1: main streaming reduction ----------------
// Software-pipelined, prefetch distance 2: while computing tile t, tile t+1 is
// resident and tile t+2's loads are in flight (8 outstanding float4 loads).
__global__ __launch_bounds__(THREADS, 8) void loss_main_kernel(
    const float4* __restrict__ pp4,
    const float4* __restrict__ pt4,
    const float4* __restrict__ md4,
    const float4* __restrict__ tg4,
    const float*  __restrict__ Vp,
    float2*       __restrict__ partials,
    int n4)
{
    const float V = Vp[0];
    float phys = 0.0f;
    float lm   = 0.0f;

    const int tid = blockIdx.x * THREADS + threadIdx.x;

    if (tid + STRIDE < n4) {
        // prologue: tiles 0 and 1
        float4 a0 = pp4[tid];
        float4 b0 = pt4[tid];
        float4 c0 = md4[tid];
        float4 d0 = tg4[tid];
        float4 a1 = pp4[tid + STRIDE];
        float4 b1 = pt4[tid + STRIDE];
        float4 c1 = md4[tid + STRIDE];
        float4 d1 = tg4[tid + STRIDE];

        for (int i = tid + 2 * STRIDE; i < n4; i += STRIDE) {
            // issue tile t+2's loads
            float4 a2 = pp4[i];
            float4 b2 = pt4[i];
            float4 c2 = md4[i];
            float4 d2 = tg4[i];
            // compute tile t (t+1 resident, t+2 in flight)
            accum_vec4(a0, b0, c0, d0, V, phys, lm);
            a0 = a1; b0 = b1; c0 = c1; d0 = d1;
            a1 = a2; b1 = b2; c1 = c2; d1 = d2;
        }
        accum_vec4(a0, b0, c0, d0, V, phys, lm);
        accum_vec4(a1, b1, c1, d1, V, phys, lm);
    } else if (tid < n4) {
        float4 a = pp4[tid];
        float4 b = pt4[tid];
        float4 c = md4[tid];
        float4 d = tg4[tid];
        accum_vec4(a, b, c, d, V, phys, lm);
    }

    phys = wave_reduce(phys);
    lm   = wave_reduce(lm);

    __shared__ float sp[4];
    __shared__ float sl[4];
    int lane = threadIdx.x & 63;
    int w    = threadIdx.x >> 6;
    if (lane == 0) { sp[w] = phys; sl[w] = lm; }
    __syncthreads();
    if (threadIdx.x == 0) {
        float P = sp[0] + sp[1] + sp[2] + sp[3];
        float L = sl[0] + sl[1] + sl[2] + sl[3];
        partials[blockIdx.x] = make_float2(P, L);
    }
}

// ---------------- Kernel 2: final reduce + BCE + compose ----------------
// 1024 threads (16 waves): the tail is latency-bound, throw waves at it.
__global__ __launch_bounds__(FTHREADS) void loss_finish_kernel(
    const float4* __restrict__ partials4, int nblk4, // (P0,L0,P1,L1) per elem
    const float*  __restrict__ logit,
    const float*  __restrict__ yf,
    int nb,
    float*        __restrict__ out,
    float inv_ns)
{
    float phys = 0.0f, lm = 0.0f, cls = 0.0f;

    for (int i = threadIdx.x; i < nblk4; i += FTHREADS) {
        float4 p = partials4[i];
        phys += p.x + p.z;
        lm   += p.y + p.w;
    }
    for (int i = threadIdx.x; i < nb; i += FTHREADS) {
        float x = logit[i];
        float y = yf[i];
        cls += fmaxf(x, 0.0f) - x * y + log1pf(__expf(-fabsf(x)));
    }

    phys = wave_reduce(phys);
    lm   = wave_reduce(lm);
    cls  = wave_reduce(cls);

    __shared__ float sp[16], sl[16], sc[16];
    int lane = threadIdx.x & 63;
    int w    = threadIdx.x >> 6;
    if (lane == 0) { sp[w] = phys; sl[w] = lm; sc[w] = cls; }
    __syncthreads();
    if (threadIdx.x == 0) {
        float P = 0.0f, L = 0.0f, C = 0.0f;
        #pragma unroll
        for (int k = 0; k < 16; ++k) { P += sp[k]; L += sl[k]; C += sc[k]; }

        float loss_physics = P * inv_ns;
        float loss_M       = L * inv_ns;
        float loss_cls     = C / (float)nb;

        out[0] = loss_M + 0.5f * loss_physics + 0.5f * loss_cls;
        out[1] = loss_M;
        out[2] = loss_physics;
        out[3] = loss_cls;
    }
}

extern "C" void kernel_launch(void* const* d_in, const int* in_sizes, int n_in,
                              void* d_out, int out_size, void* d_ws, size_t ws_size,
                              hipStream_t stream) {
    const float* p_pred   = (const float*)d_in[0];
    const float* p_t_pred = (const float*)d_in[1];
    const float* logit    = (const float*)d_in[2];
    const float* yfault   = (const float*)d_in[3];
    const float* mdot_A   = (const float*)d_in[4];
    const float* tgt_p    = (const float*)d_in[5];
    const float* V        = (const float*)d_in[6];

    int n  = in_sizes[0];       // B*S = 8388608
    int nb = in_sizes[3];       // B = 512
    int n4 = n / 4;

    float2* partials = (float2*)d_ws;

    loss_main_kernel<<<BLOCKS, THREADS, 0, stream>>>(
        (const float4*)p_pred, (const float4*)p_t_pred,
        (const float4*)mdot_A, (const float4*)tgt_p,
        V, partials, n4);

    loss_finish_kernel<<<1, FTHREADS, 0, stream>>>(
        (const float4*)partials, BLOCKS / 2, logit, yfault, nb,
        (float*)d_out, 1.0f / (float)n);
}

// Round 10
// 28.495 us; speedup vs baseline: 1.1400x; 1.1400x over previous
//
#include <hip/hip_runtime.h>
#include <math.h>

#define THREADS 256
#define FTHREADS 1024

__device__ __forceinline__ float wave_reduce(float v) {
    #pragma unroll
    for (int off = 32; off > 0; off >>= 1)
        v += __shfl_down(v, off, 64);
    return v;
}

__device__ __forceinline__ void accum_elem(float pp, float pt, float md, float tg,
                                           float V, float& phys, float& lm) {
    constexpr float P_ATM    = 0.101325f;
    constexpr float BETA     = 1466.96f;
    constexpr float INV_BETA = 1.0f / 1466.96f;
    constexpr float R_FRAC   = 0.005f / 0.995f;
    constexpr float C_RP     = R_FRAC * P_ATM;
    constexpr float RHO_MIX  = 851.6f + 1.225f * R_FRAC;
    constexpr float PT_EPS   = 1e-12f;

    float p_used  = fmaxf(pp * 0.1f, 1.0f);
    float inv_pu  = __builtin_amdgcn_rcpf(p_used);
    float p_denom = C_RP * inv_pu;
    float p_ratio = p_denom * inv_pu;
    float e       = __expf((P_ATM - p_used) * INV_BETA) * INV_BETA;
    float denom   = BETA * e + p_denom;
    float inv_d   = __builtin_amdgcn_rcpf(denom);
    float drho    = RHO_MIX * (e + p_ratio) * inv_d * inv_d;

    float res  = V * drho * pt - md;
    bool  m    = fabsf(pt) >= PT_EPS;
    phys += m ? fabsf(res)     : 0.0f;
    lm   += m ? fabsf(tg - pp) : 0.0f;
}

// ---------------- Kernel 1: one float4 tile per thread ----------------
// No grid-stride loop: each wave issues its 4 loads, computes, retires.
// MLP comes from wave turnover; thread->address map is fully contiguous.
__global__ __launch_bounds__(THREADS) void loss_main_kernel(
    const float4* __restrict__ pp4,
    const float4* __restrict__ pt4,
    const float4* __restrict__ md4,
    const float4* __restrict__ tg4,
    const float*  __restrict__ Vp,
    float2*       __restrict__ partials,
    int n4)
{
    const float V = Vp[0];
    float phys = 0.0f;
    float lm   = 0.0f;

    const int i = blockIdx.x * THREADS + threadIdx.x;

    if (i < n4) {
        float4 a = pp4[i];
        float4 b = pt4[i];
        float4 c = md4[i];
        float4 d = tg4[i];
        accum_elem(a.x, b.x, c.x, d.x, V, phys, lm);
        accum_elem(a.y, b.y, c.y, d.y, V, phys, lm);
        accum_elem(a.z, b.z, c.z, d.z, V, phys, lm);
        accum_elem(a.w, b.w, c.w, d.w, V, phys, lm);
    }

    phys = wave_reduce(phys);
    lm   = wave_reduce(lm);

    __shared__ float sp[4];
    __shared__ float sl[4];
    int lane = threadIdx.x & 63;
    int w    = threadIdx.x >> 6;
    if (lane == 0) { sp[w] = phys; sl[w] = lm; }
    __syncthreads();
    if (threadIdx.x == 0) {
        float P = sp[0] + sp[1] + sp[2] + sp[3];
        float L = sl[0] + sl[1] + sl[2] + sl[3];
        partials[blockIdx.x] = make_float2(P, L);
    }
}

// ---------------- Kernel 2: final reduce + BCE + compose ----------------
__global__ __launch_bounds__(FTHREADS) void loss_finish_kernel(
    const float4* __restrict__ partials4, int nblk4, // (P0,L0,P1,L1) per elem
    const float*  __restrict__ logit,
    const float*  __restrict__ yf,
    int nb,
    float*        __restrict__ out,
    float inv_ns)
{
    float phys = 0.0f, lm = 0.0f, cls = 0.0f;

    for (int i = threadIdx.x; i < nblk4; i += FTHREADS) {
        float4 p = partials4[i];
        phys += p.x + p.z;
        lm   += p.y + p.w;
    }
    for (int i = threadIdx.x; i < nb; i += FTHREADS) {
        float x = logit[i];
        float y = yf[i];
        cls += fmaxf(x, 0.0f) - x * y + log1pf(__expf(-fabsf(x)));
    }

    phys = wave_reduce(phys);
    lm   = wave_reduce(lm);
    cls  = wave_reduce(cls);

    __shared__ float sp[16], sl[16], sc[16];
    int lane = threadIdx.x & 63;
    int w    = threadIdx.x >> 6;
    if (lane == 0) { sp[w] = phys; sl[w] = lm; sc[w] = cls; }
    __syncthreads();
    if (threadIdx.x == 0) {
        float P = 0.0f, L = 0.0f, C = 0.0f;
        #pragma unroll
        for (int k = 0; k < 16; ++k) { P += sp[k]; L += sl[k]; C += sc[k]; }

        float loss_physics = P * inv_ns;
        float loss_M       = L * inv_ns;
        float loss_cls     = C / (float)nb;

        out[0] = loss_M + 0.5f * loss_physics + 0.5f * loss_cls;
        out[1] = loss_M;
        out[2] = loss_physics;
        out[3] = loss_cls;
    }
}

extern "C" void kernel_launch(void* const* d_in, const int* in_sizes, int n_in,
                              void* d_out, int out_size, void* d_ws, size_t ws_size,
                              hipStream_t stream) {
    const float* p_pred   = (const float*)d_in[0];
    const float* p_t_pred = (const float*)d_in[1];
    const float* logit    = (const float*)d_in[2];
    const float* yfault   = (const float*)d_in[3];
    const float* mdot_A   = (const float*)d_in[4];
    const float* tgt_p    = (const float*)d_in[5];
    const float* V        = (const float*)d_in[6];

    int n  = in_sizes[0];       // B*S = 8388608
    int nb = in_sizes[3];       // B = 512
    int n4 = n / 4;             // 2097152

    int blocks = (n4 + THREADS - 1) / THREADS;   // 8192

    float2* partials = (float2*)d_ws;            // 8192 * 8 B = 64 KB

    loss_main_kernel<<<blocks, THREADS, 0, stream>>>(
        (const float4*)p_pred, (const float4*)p_t_pred,
        (const float4*)mdot_A, (const float4*)tgt_p,
        V, partials, n4);

    loss_finish_kernel<<<1, FTHREADS, 0, stream>>>(
        (const float4*)partials, blocks / 2, logit, yfault, nb,
        (float*)d_out, 1.0f / (float)n);
}